// Round 3
// baseline (383.117 us; speedup 1.0000x reference)
//
#include <hip/hip_runtime.h>
#include <stdint.h>

typedef unsigned short u16;
typedef __attribute__((ext_vector_type(8))) short bfrag;   // 8 x bf16 (4 VGPRs)
typedef __attribute__((ext_vector_type(4))) float f32x4;   // MFMA C/D

#define MFMA_BF16 __builtin_amdgcn_mfma_f32_16x16x32_bf16

static constexpr int Bc = 2;      // batch
static constexpr int Tc = 2048;   // seq
static constexpr int Cc = 1024;   // channels
static constexpr int Hc = 16;     // heads
static constexpr int Dc = 64;     // head dim
static constexpr size_t QSZ = (size_t)Bc * Hc * Tc * Dc;  // 4,194,304 elems
static constexpr float NEG = -1e30f;

__device__ __forceinline__ u16 f2bf(float f) {
    union { unsigned int i; float f; } v; v.f = f;
    unsigned int u = v.i;
    u += 0x7fffu + ((u >> 16) & 1u);   // round-to-nearest-even
    return (u16)(u >> 16);
}

// ---------------------------------------------------------------------------
// fp32 -> bf16 elementwise convert (n divisible by 4*256)
// ---------------------------------------------------------------------------
__global__ void cvt_f32_bf16(const float* __restrict__ in, u16* __restrict__ out) {
    const int i = (blockIdx.x * 256 + threadIdx.x) * 4;
    const float4 v = *(const float4*)(in + i);
    ushort4 o;
    o.x = f2bf(v.x); o.y = f2bf(v.y); o.z = f2bf(v.z); o.w = f2bf(v.w);
    *(ushort4*)(out + i) = o;
}

// ---------------------------------------------------------------------------
// Weight transpose+convert: in fp32 [rows][cols] -> out bf16 [cols][rows]
// ---------------------------------------------------------------------------
__global__ void transpose_f32_bf16(const float* __restrict__ in, u16* __restrict__ out,
                                   int rows, int cols) {
    __shared__ u16 tile[32][33];
    int c0 = blockIdx.x * 32, r0 = blockIdx.y * 32;
    int tx = threadIdx.x, ty = threadIdx.y;   // (32, 8)
    for (int i = 0; i < 4; i++)
        tile[ty + 8 * i][tx] = f2bf(in[(size_t)(r0 + ty + 8 * i) * cols + c0 + tx]);
    __syncthreads();
    for (int i = 0; i < 4; i++)
        out[(size_t)(c0 + ty + 8 * i) * rows + r0 + tx] = tile[tx][ty + 8 * i];
}

// ---------------------------------------------------------------------------
// GEMM: C[M][N] = A[M][K] @ B[K][N] + bias, with B supplied transposed: BT[N][K]
// A, BT bf16; bias fp32. 128x128 tile, BK=32, 256 threads, 4x4 16x16x32 MFMA/wave.
// MODE 0: out fp32 row-major [M][N].
// MODE 1: QKV scatter: Q,K -> bf16 [B*H][T][D]; V -> TRANSPOSED bf16 [B*H][D][T].
// ---------------------------------------------------------------------------
template <int MODE>
__global__ __launch_bounds__(256) void gemm_bt(
    const u16* __restrict__ A, const u16* __restrict__ BT,
    const float* __restrict__ bias, void* __restrict__ out_p,
    int M, int Nn, int K) {
    __shared__ __align__(16) u16 As[128][40];
    __shared__ __align__(16) u16 Bs[128][40];

    const int tid  = threadIdx.x;
    const int wave = tid >> 6, lane = tid & 63;
    const int quad = lane >> 4, l16 = lane & 15;
    const int wm = wave & 1, wn = wave >> 1;
    const int m0 = blockIdx.y * 128, n0 = blockIdx.x * 128;

    f32x4 acc[4][4];
    for (int i = 0; i < 4; i++)
        for (int j = 0; j < 4; j++)
            acc[i][j] = (f32x4){0.f, 0.f, 0.f, 0.f};

    const int srow = tid >> 2;            // 0..63
    const int scol = (tid & 3) << 3;      // 0,8,16,24

    for (int k0 = 0; k0 < K; k0 += 32) {
        uint4 a0 = *(const uint4*)(A  + (size_t)(m0 + srow)      * K + k0 + scol);
        uint4 a1 = *(const uint4*)(A  + (size_t)(m0 + srow + 64) * K + k0 + scol);
        uint4 b0 = *(const uint4*)(BT + (size_t)(n0 + srow)      * K + k0 + scol);
        uint4 b1 = *(const uint4*)(BT + (size_t)(n0 + srow + 64) * K + k0 + scol);
        __syncthreads();
        *(uint4*)&As[srow][scol]      = a0;
        *(uint4*)&As[srow + 64][scol] = a1;
        *(uint4*)&Bs[srow][scol]      = b0;
        *(uint4*)&Bs[srow + 64][scol] = b1;
        __syncthreads();

        bfrag af[4], bf[4];
        for (int mt = 0; mt < 4; mt++)
            af[mt] = *(const bfrag*)&As[wm * 64 + mt * 16 + l16][quad * 8];
        for (int nt = 0; nt < 4; nt++)
            bf[nt] = *(const bfrag*)&Bs[wn * 64 + nt * 16 + l16][quad * 8];
        for (int mt = 0; mt < 4; mt++)
            for (int nt = 0; nt < 4; nt++)
                acc[mt][nt] = MFMA_BF16(af[mt], bf[nt], acc[mt][nt], 0, 0, 0);
    }

    // epilogue
    for (int nt = 0; nt < 4; nt++) {
        const int gn = n0 + wn * 64 + nt * 16 + l16;
        const float bv = bias[gn];
        if (MODE == 1) {
            u16* out = (u16*)out_p;
            const int comp = gn >> 10, rem = gn & 1023;
            const int hh = rem >> 6, dd = rem & 63;
            for (int mt = 0; mt < 4; mt++) {
                for (int r = 0; r < 4; r++) {
                    const int gm = m0 + wm * 64 + mt * 16 + quad * 4 + r;
                    const int bb = gm >> 11, tt = gm & 2047;
                    const u16 val = f2bf(acc[mt][nt][r] + bv);
                    if (comp < 2) {
                        // Q/K: [B*H][T][D]
                        out[(size_t)comp * QSZ +
                            ((size_t)(bb * Hc + hh) * Tc + tt) * Dc + dd] = val;
                    } else {
                        // V transposed: [B*H][D][T]
                        out[2 * QSZ +
                            ((size_t)(bb * Hc + hh) * Dc + dd) * Tc + tt] = val;
                    }
                }
            }
        } else {
            float* out = (float*)out_p;
            for (int mt = 0; mt < 4; mt++) {
                for (int r = 0; r < 4; r++) {
                    const int gm = m0 + wm * 64 + mt * 16 + quad * 4 + r;
                    out[(size_t)gm * Nn + gn] = acc[mt][nt][r] + bv;
                }
            }
        }
    }
}

// ---------------------------------------------------------------------------
// Barrier-free causal flash attention.
// Q,K: [B*H][T][D] bf16.  Vt: [B*H][D][T] bf16.  O: [B*T][C] bf16.
// One fully independent wave per 16 Q-rows; 64-key tiles; K/Vt fragments
// loaded directly from global (L2-resident); P via per-wave private LDS.
// ---------------------------------------------------------------------------
__global__ __launch_bounds__(256, 4) void attn_kernel(
    const u16* __restrict__ Qb, const u16* __restrict__ Kb,
    const u16* __restrict__ Vt, u16* __restrict__ Ob) {
    __shared__ __align__(16) u16 Ps[4][16][72];   // per-wave P tile [q][key]

    const int tid  = threadIdx.x;
    const int wave = tid >> 6, lane = tid & 63;
    const int quad = lane >> 4, l16 = lane & 15;

    const int gwave = blockIdx.x * 4 + wave;      // 0..4095
    const int bh = gwave >> 7;                    // b*H + h
    const int qw = (gwave & 127) * 16;            // this wave's base q row
    const u16* Kp = Kb + (size_t)bh * Tc * Dc;
    const u16* Vp = Vt + (size_t)bh * Dc * Tc;

    // Q fragments (A-layout): A[m=l16][k=quad*8+j], two 32-wide k groups
    bfrag qf0, qf1;
    {
        const u16* qp = Qb + (size_t)bh * Tc * Dc + (size_t)(qw + l16) * Dc + quad * 8;
        qf0 = *(const bfrag*)qp;
        qf1 = *(const bfrag*)(qp + 32);
    }

    float m_i[4], l_i[4];
    f32x4 oacc[4];
    for (int r = 0; r < 4; r++) { m_i[r] = NEG; l_i[r] = 0.f; }
    for (int g = 0; g < 4; g++) oacc[g] = (f32x4){0.f, 0.f, 0.f, 0.f};

    auto process = [&](int k0, bool domask) __attribute__((always_inline)) {
        // ---- S = Q @ K^T : 16 q-rows x 64 keys (4 col-groups of 16) ----
        f32x4 s[4];
        #pragma unroll
        for (int g = 0; g < 4; g++) {
            const u16* kp = Kp + (size_t)(k0 + g * 16 + l16) * Dc + quad * 8;
            bfrag kf0 = *(const bfrag*)kp;
            bfrag kf1 = *(const bfrag*)(kp + 32);
            f32x4 z = (f32x4){0.f, 0.f, 0.f, 0.f};
            z = MFMA_BF16(qf0, kf0, z, 0, 0, 0);
            z = MFMA_BF16(qf1, kf1, z, 0, 0, 0);
            s[g] = z;
        }
        // ---- V fragments (independent of softmax -> issue early) ----
        bfrag vf0[4], vf1[4];
        #pragma unroll
        for (int ng = 0; ng < 4; ng++) {
            const u16* vp = Vp + (size_t)(ng * 16 + l16) * Tc + k0 + quad * 8;
            vf0[ng] = *(const bfrag*)vp;
            vf1[ng] = *(const bfrag*)(vp + 32);
        }
        // ---- online softmax over the 64 columns ----
        #pragma unroll
        for (int r = 0; r < 4; r++) {
            const int rowq = qw + quad * 4 + r;
            #pragma unroll
            for (int g = 0; g < 4; g++) {
                float v = s[g][r] * 0.125f;
                if (domask) {
                    const int col = k0 + g * 16 + l16;
                    if (col > rowq) v = NEG;
                }
                s[g][r] = v;
            }
            float t = fmaxf(fmaxf(s[0][r], s[1][r]), fmaxf(s[2][r], s[3][r]));
            #pragma unroll
            for (int off = 1; off < 16; off <<= 1)
                t = fmaxf(t, __shfl_xor(t, off));
            const float mnew = fmaxf(m_i[r], t);
            const float alpha = __expf(m_i[r] - mnew);
            m_i[r] = mnew;
            float rs = 0.f;
            #pragma unroll
            for (int g = 0; g < 4; g++) {
                const float p = __expf(s[g][r] - mnew);
                s[g][r] = p;
                rs += p;
            }
            #pragma unroll
            for (int off = 1; off < 16; off <<= 1)
                rs += __shfl_xor(rs, off);
            l_i[r] = l_i[r] * alpha + rs;
            #pragma unroll
            for (int g = 0; g < 4; g++)
                oacc[g][r] *= alpha;
            // P: C-layout -> LDS (per-wave private slab, padded to 72)
            #pragma unroll
            for (int g = 0; g < 4; g++)
                Ps[wave][quad * 4 + r][g * 16 + l16] = f2bf(s[g][r]);
        }
        __asm__ __volatile__("s_waitcnt lgkmcnt(0)" ::: "memory");
        // ---- O += P @ V : A-layout P, B-layout Vt ----
        bfrag pf0 = *(const bfrag*)&Ps[wave][l16][quad * 8];
        bfrag pf1 = *(const bfrag*)&Ps[wave][l16][32 + quad * 8];
        #pragma unroll
        for (int ng = 0; ng < 4; ng++) {
            oacc[ng] = MFMA_BF16(pf0, vf0[ng], oacc[ng], 0, 0, 0);
            oacc[ng] = MFMA_BF16(pf1, vf1[ng], oacc[ng], 0, 0, 0);
        }
    };

    const int nf = qw >> 6;        // tiles fully below the diagonal
    int k0 = 0;
    for (int t = 0; t < nf; t++, k0 += 64) process(k0, false);
    process(k0, true);             // the one diagonal (masked) tile

    // epilogue: O /= l, write to [B*T][C] at col h*64 + d
    const int b = bh >> 4, h = bh & 15;
    #pragma unroll
    for (int r = 0; r < 4; r++) {
        const float inv = 1.f / l_i[r];
        const int q = qw + quad * 4 + r;
        u16* orow = Ob + (size_t)(b * Tc + q) * Cc + h * 64;
        #pragma unroll
        for (int ng = 0; ng < 4; ng++)
            orow[ng * 16 + l16] = f2bf(oacc[ng][r] * inv);
    }
}

// ---------------------------------------------------------------------------
extern "C" void kernel_launch(void* const* d_in, const int* in_sizes, int n_in,
                              void* d_out, int out_size, void* d_ws, size_t ws_size,
                              hipStream_t stream) {
    const float* x     = (const float*)d_in[0];   // [B*T][C] fp32
    const float* w_qkv = (const float*)d_in[1];   // [C][3C] fp32
    const float* b_qkv = (const float*)d_in[2];   // [3C] fp32
    const float* w_out = (const float*)d_in[3];   // [C][C] fp32
    const float* b_out = (const float*)d_in[4];   // [C] fp32
    float* out = (float*)d_out;                   // [B*T][C] fp32
    u16* ws  = (u16*)d_ws;

    u16* xb    = ws;                               // 4096*1024 bf16
    u16* WqkvT = xb    + (size_t)4096 * 1024;      // [3072][1024]
    u16* WoutT = WqkvT + (size_t)3072 * 1024;      // [1024][1024]
    u16* Qb    = WoutT + (size_t)1024 * 1024;      // [B*H][T][D]
    u16* Kb    = Qb + QSZ;                         // [B*H][T][D]
    u16* Vt    = Kb + QSZ;                         // [B*H][D][T] (transposed!)
    u16* Ao    = Vt + QSZ;                         // [B*T][C] bf16

    cvt_f32_bf16<<<4096 * 1024 / (4 * 256), 256, 0, stream>>>(x, xb);
    transpose_f32_bf16<<<dim3(3072 / 32, 1024 / 32), dim3(32, 8), 0, stream>>>(
        w_qkv, WqkvT, 1024, 3072);
    transpose_f32_bf16<<<dim3(1024 / 32, 1024 / 32), dim3(32, 8), 0, stream>>>(
        w_out, WoutT, 1024, 1024);
    gemm_bt<1><<<dim3(3072 / 128, 4096 / 128), 256, 0, stream>>>(
        xb, WqkvT, b_qkv, Qb, 4096, 3072, 1024);
    attn_kernel<<<1024, 256, 0, stream>>>(Qb, Kb, Vt, Ao);
    gemm_bt<0><<<dim3(1024 / 128, 4096 / 128), 256, 0, stream>>>(
        Ao, WoutT, b_out, out, 4096, 1024, 1024);
}

// Round 4
// 225.659 us; speedup vs baseline: 1.6978x; 1.6978x over previous
//
#include <hip/hip_runtime.h>
#include <stdint.h>

typedef unsigned short u16;
typedef __attribute__((ext_vector_type(8))) short bfrag;   // 8 x bf16 (4 VGPRs)
typedef __attribute__((ext_vector_type(4))) float f32x4;   // MFMA C/D

#define MFMA_BF16 __builtin_amdgcn_mfma_f32_16x16x32_bf16

static constexpr int Bc = 2;      // batch
static constexpr int Tc = 2048;   // seq
static constexpr int Cc = 1024;   // channels
static constexpr int Hc = 16;     // heads
static constexpr int Dc = 64;     // head dim
static constexpr size_t QSZ = (size_t)Bc * Hc * Tc * Dc;  // 4,194,304 elems
static constexpr float NEG = -1e30f;

__device__ __forceinline__ u16 f2bf(float f) {
    union { unsigned int i; float f; } v; v.f = f;
    unsigned int u = v.i;
    u += 0x7fffu + ((u >> 16) & 1u);   // round-to-nearest-even
    return (u16)(u >> 16);
}

// async global -> LDS, 16B per lane. lds base must be wave-uniform; HW deposits
// at lds + lane*16.
__device__ __forceinline__ void async_load16(const u16* g, u16* lds) {
    __builtin_amdgcn_global_load_lds(
        (const __attribute__((address_space(1))) unsigned int*)g,
        (__attribute__((address_space(3))) unsigned int*)lds, 16, 0, 0);
}

// ---------------------------------------------------------------------------
// fp32 -> bf16 elementwise convert (n divisible by 4*256)
// ---------------------------------------------------------------------------
__global__ void cvt_f32_bf16(const float* __restrict__ in, u16* __restrict__ out) {
    const int i = (blockIdx.x * 256 + threadIdx.x) * 4;
    const float4 v = *(const float4*)(in + i);
    ushort4 o;
    o.x = f2bf(v.x); o.y = f2bf(v.y); o.z = f2bf(v.z); o.w = f2bf(v.w);
    *(ushort4*)(out + i) = o;
}

// ---------------------------------------------------------------------------
// Weight transpose+convert: in fp32 [rows][cols] -> out bf16 [cols][rows]
// ---------------------------------------------------------------------------
__global__ void transpose_f32_bf16(const float* __restrict__ in, u16* __restrict__ out,
                                   int rows, int cols) {
    __shared__ u16 tile[32][33];
    int c0 = blockIdx.x * 32, r0 = blockIdx.y * 32;
    int tx = threadIdx.x, ty = threadIdx.y;   // (32, 8)
    for (int i = 0; i < 4; i++)
        tile[ty + 8 * i][tx] = f2bf(in[(size_t)(r0 + ty + 8 * i) * cols + c0 + tx]);
    __syncthreads();
    for (int i = 0; i < 4; i++)
        out[(size_t)(c0 + ty + 8 * i) * rows + r0 + tx] = tile[tx][ty + 8 * i];
}

// ---------------------------------------------------------------------------
// GEMM: C[M][N] = A[M][K] @ B[K][N] + bias, with B supplied transposed: BT[N][K]
// A, BT bf16; bias fp32. 128x128 tile, BK=32, 256 threads, 4x4 16x16x32 MFMA/wave.
// MODE 0: out fp32 row-major [M][N].
// MODE 1: QKV scatter: Q,K -> bf16 [B*H][T][D]; V -> TRANSPOSED bf16 [B*H][D][T].
// ---------------------------------------------------------------------------
template <int MODE>
__global__ __launch_bounds__(256) void gemm_bt(
    const u16* __restrict__ A, const u16* __restrict__ BT,
    const float* __restrict__ bias, void* __restrict__ out_p,
    int M, int Nn, int K) {
    __shared__ __align__(16) u16 As[128][40];
    __shared__ __align__(16) u16 Bs[128][40];

    const int tid  = threadIdx.x;
    const int wave = tid >> 6, lane = tid & 63;
    const int quad = lane >> 4, l16 = lane & 15;
    const int wm = wave & 1, wn = wave >> 1;
    const int m0 = blockIdx.y * 128, n0 = blockIdx.x * 128;

    f32x4 acc[4][4];
    for (int i = 0; i < 4; i++)
        for (int j = 0; j < 4; j++)
            acc[i][j] = (f32x4){0.f, 0.f, 0.f, 0.f};

    const int srow = tid >> 2;            // 0..63
    const int scol = (tid & 3) << 3;      // 0,8,16,24

    for (int k0 = 0; k0 < K; k0 += 32) {
        uint4 a0 = *(const uint4*)(A  + (size_t)(m0 + srow)      * K + k0 + scol);
        uint4 a1 = *(const uint4*)(A  + (size_t)(m0 + srow + 64) * K + k0 + scol);
        uint4 b0 = *(const uint4*)(BT + (size_t)(n0 + srow)      * K + k0 + scol);
        uint4 b1 = *(const uint4*)(BT + (size_t)(n0 + srow + 64) * K + k0 + scol);
        __syncthreads();
        *(uint4*)&As[srow][scol]      = a0;
        *(uint4*)&As[srow + 64][scol] = a1;
        *(uint4*)&Bs[srow][scol]      = b0;
        *(uint4*)&Bs[srow + 64][scol] = b1;
        __syncthreads();

        bfrag af[4], bf[4];
        for (int mt = 0; mt < 4; mt++)
            af[mt] = *(const bfrag*)&As[wm * 64 + mt * 16 + l16][quad * 8];
        for (int nt = 0; nt < 4; nt++)
            bf[nt] = *(const bfrag*)&Bs[wn * 64 + nt * 16 + l16][quad * 8];
        for (int mt = 0; mt < 4; mt++)
            for (int nt = 0; nt < 4; nt++)
                acc[mt][nt] = MFMA_BF16(af[mt], bf[nt], acc[mt][nt], 0, 0, 0);
    }

    // epilogue
    for (int nt = 0; nt < 4; nt++) {
        const int gn = n0 + wn * 64 + nt * 16 + l16;
        const float bv = bias[gn];
        if (MODE == 1) {
            u16* out = (u16*)out_p;
            const int comp = gn >> 10, rem = gn & 1023;
            const int hh = rem >> 6, dd = rem & 63;
            for (int mt = 0; mt < 4; mt++) {
                for (int r = 0; r < 4; r++) {
                    const int gm = m0 + wm * 64 + mt * 16 + quad * 4 + r;
                    const int bb = gm >> 11, tt = gm & 2047;
                    const u16 val = f2bf(acc[mt][nt][r] + bv);
                    if (comp < 2) {
                        // Q/K: [B*H][T][D]
                        out[(size_t)comp * QSZ +
                            ((size_t)(bb * Hc + hh) * Tc + tt) * Dc + dd] = val;
                    } else {
                        // V transposed: [B*H][D][T]
                        out[2 * QSZ +
                            ((size_t)(bb * Hc + hh) * Dc + dd) * Tc + tt] = val;
                    }
                }
            }
        } else {
            float* out = (float*)out_p;
            for (int mt = 0; mt < 4; mt++) {
                for (int r = 0; r < 4; r++) {
                    const int gm = m0 + wm * 64 + mt * 16 + quad * 4 + r;
                    out[(size_t)gm * Nn + gn] = acc[mt][nt][r] + bv;
                }
            }
        }
    }
}

// ---------------------------------------------------------------------------
// Causal flash attention, block-cooperative LDS staging.
// Q,K: [B*H][T][D] bf16.  Vt: [B*H][D][T] bf16.  O: [B*T][C] bf16.
// 512 blocks: bh = blk%32 (XCD-local slabs), pair q-tiles (pr, 31-pr) -> every
// block processes exactly 33 64-key tiles (no tail). K/Vt staged via
// global_load_lds width=16 with XOR-chunk swizzle (no padding allowed).
// ---------------------------------------------------------------------------
__global__ __launch_bounds__(256, 2) void attn_kernel(
    const u16* __restrict__ Qb, const u16* __restrict__ Kb,
    const u16* __restrict__ Vt, u16* __restrict__ Ob) {
    __shared__ __align__(16) u16 KsF[64 * 64];    // [key][d-chunk-swizzled]
    __shared__ __align__(16) u16 VsF[64 * 64];    // [d][key-chunk-swizzled]
    __shared__ __align__(16) u16 Ps[4][16][72];   // per-wave P tile [q][key]

    const int tid  = threadIdx.x;
    const int wave = tid >> 6, lane = tid & 63;
    const int quad = lane >> 4, l16 = lane & 15;

    const int bh = blockIdx.x & 31;               // same-XCD head grouping
    const int pr = blockIdx.x >> 5;               // 0..15 -> q-tiles pr, 31-pr
    const u16* Qp = Qb + (size_t)bh * Tc * Dc;
    const u16* Kp = Kb + (size_t)bh * Tc * Dc;
    const u16* Vp = Vt + (size_t)bh * Dc * Tc;

    // staging lane geometry: 1KB/instr = 8 rows x 8 chunks of 16B
    const int row8 = lane >> 3;                   // 0..7
    const int swz  = ((lane & 7) ^ row8) * 8;     // swizzled chunk (elems)
    // fragment-read chunk offsets (elems), un-swizzling by row&7 == l16&7
    const int pk0 = ((quad)     ^ (l16 & 7)) * 8;
    const int pk1 = ((quad + 4) ^ (l16 & 7)) * 8;

    const int b = bh >> 4, h = bh & 15;

    for (int phase = 0; phase < 2; phase++) {
        const int jq = phase ? (31 - pr) : pr;    // q-tile index, 64 rows
        const int qw = jq * 64 + wave * 16;       // this wave's base q row

        // Q fragments (A-layout): A[m=l16][k=quad*8+j]
        bfrag qf0, qf1;
        {
            const u16* qp = Qp + (size_t)(qw + l16) * Dc + quad * 8;
            qf0 = *(const bfrag*)qp;
            qf1 = *(const bfrag*)(qp + 32);
        }

        float m_i[4], l_i[4];
        f32x4 oacc[4];
        for (int r = 0; r < 4; r++) { m_i[r] = NEG; l_i[r] = 0.f; }
        for (int g = 0; g < 4; g++) oacc[g] = (f32x4){0.f, 0.f, 0.f, 0.f};

        for (int t = 0; t <= jq; t++) {
            const int k0 = t * 64;
            // ---- stage K tile [64 keys][64 d] and Vt tile [64 d][64 keys] ----
            #pragma unroll
            for (int j = 0; j < 2; j++) {
                const int rr = wave * 16 + j * 8;          // wave-uniform row base
                const int gr = rr + row8;                  // per-lane row
                async_load16(Kp + (size_t)(k0 + gr) * Dc + swz, KsF + rr * 64);
                async_load16(Vp + (size_t)gr * Tc + k0 + swz, VsF + rr * 64);
            }
            __syncthreads();   // drains vmcnt -> LDS tiles valid

            const bool domask = (t == jq);
            // ---- S = Q @ K^T : 16 q-rows x 64 keys ----
            f32x4 s[4];
            #pragma unroll
            for (int g = 0; g < 4; g++) {
                const u16* kb = KsF + (g * 16 + l16) * 64;
                bfrag kf0 = *(const bfrag*)(kb + pk0);
                bfrag kf1 = *(const bfrag*)(kb + pk1);
                f32x4 z = (f32x4){0.f, 0.f, 0.f, 0.f};
                z = MFMA_BF16(qf0, kf0, z, 0, 0, 0);
                z = MFMA_BF16(qf1, kf1, z, 0, 0, 0);
                s[g] = z;
            }
            // ---- online softmax over the 64 columns ----
            #pragma unroll
            for (int r = 0; r < 4; r++) {
                const int rowq = qw + quad * 4 + r;
                #pragma unroll
                for (int g = 0; g < 4; g++) {
                    float v = s[g][r] * 0.125f;
                    if (domask) {
                        const int col = k0 + g * 16 + l16;
                        if (col > rowq) v = NEG;
                    }
                    s[g][r] = v;
                }
                float tm = fmaxf(fmaxf(s[0][r], s[1][r]), fmaxf(s[2][r], s[3][r]));
                #pragma unroll
                for (int off = 1; off < 16; off <<= 1)
                    tm = fmaxf(tm, __shfl_xor(tm, off));
                const float mnew = fmaxf(m_i[r], tm);
                const float alpha = __expf(m_i[r] - mnew);
                m_i[r] = mnew;
                float rs = 0.f;
                #pragma unroll
                for (int g = 0; g < 4; g++) {
                    const float p = __expf(s[g][r] - mnew);
                    s[g][r] = p;
                    rs += p;
                }
                #pragma unroll
                for (int off = 1; off < 16; off <<= 1)
                    rs += __shfl_xor(rs, off);
                l_i[r] = l_i[r] * alpha + rs;
                #pragma unroll
                for (int g = 0; g < 4; g++)
                    oacc[g][r] *= alpha;
                #pragma unroll
                for (int g = 0; g < 4; g++)
                    Ps[wave][quad * 4 + r][g * 16 + l16] = f2bf(s[g][r]);
            }
            __asm__ __volatile__("s_waitcnt lgkmcnt(0)" ::: "memory");
            // ---- O += P @ V ----
            bfrag pf0 = *(const bfrag*)&Ps[wave][l16][quad * 8];
            bfrag pf1 = *(const bfrag*)&Ps[wave][l16][32 + quad * 8];
            #pragma unroll
            for (int ng = 0; ng < 4; ng++) {
                const u16* vb = VsF + (ng * 16 + l16) * 64;
                bfrag vf0 = *(const bfrag*)(vb + pk0);
                bfrag vf1 = *(const bfrag*)(vb + pk1);
                oacc[ng] = MFMA_BF16(pf0, vf0, oacc[ng], 0, 0, 0);
                oacc[ng] = MFMA_BF16(pf1, vf1, oacc[ng], 0, 0, 0);
            }
            __syncthreads();   // LDS reads done before next tile's staging
        }

        // epilogue: O /= l, write to [B*T][C] at col h*64 + d
        #pragma unroll
        for (int r = 0; r < 4; r++) {
            const float inv = 1.f / l_i[r];
            const int q = qw + quad * 4 + r;
            u16* orow = Ob + (size_t)(b * Tc + q) * Cc + h * 64;
            #pragma unroll
            for (int ng = 0; ng < 4; ng++)
                orow[ng * 16 + l16] = f2bf(oacc[ng][r] * inv);
        }
    }
}

// ---------------------------------------------------------------------------
extern "C" void kernel_launch(void* const* d_in, const int* in_sizes, int n_in,
                              void* d_out, int out_size, void* d_ws, size_t ws_size,
                              hipStream_t stream) {
    const float* x     = (const float*)d_in[0];   // [B*T][C] fp32
    const float* w_qkv = (const float*)d_in[1];   // [C][3C] fp32
    const float* b_qkv = (const float*)d_in[2];   // [3C] fp32
    const float* w_out = (const float*)d_in[3];   // [C][C] fp32
    const float* b_out = (const float*)d_in[4];   // [C] fp32
    float* out = (float*)d_out;                   // [B*T][C] fp32
    u16* ws  = (u16*)d_ws;

    u16* xb    = ws;                               // 4096*1024 bf16
    u16* WqkvT = xb    + (size_t)4096 * 1024;      // [3072][1024]
    u16* WoutT = WqkvT + (size_t)3072 * 1024;      // [1024][1024]
    u16* Qb    = WoutT + (size_t)1024 * 1024;      // [B*H][T][D]
    u16* Kb    = Qb + QSZ;                         // [B*H][T][D]
    u16* Vt    = Kb + QSZ;                         // [B*H][D][T] (transposed!)
    u16* Ao    = Vt + QSZ;                         // [B*T][C] bf16

    cvt_f32_bf16<<<4096 * 1024 / (4 * 256), 256, 0, stream>>>(x, xb);
    transpose_f32_bf16<<<dim3(3072 / 32, 1024 / 32), dim3(32, 8), 0, stream>>>(
        w_qkv, WqkvT, 1024, 3072);
    transpose_f32_bf16<<<dim3(1024 / 32, 1024 / 32), dim3(32, 8), 0, stream>>>(
        w_out, WoutT, 1024, 1024);
    gemm_bt<1><<<dim3(3072 / 128, 4096 / 128), 256, 0, stream>>>(
        xb, WqkvT, b_qkv, Qb, 4096, 3072, 1024);
    attn_kernel<<<512, 256, 0, stream>>>(Qb, Kb, Vt, Ao);
    gemm_bt<0><<<dim3(1024 / 128, 4096 / 128), 256, 0, stream>>>(
        Ao, WoutT, b_out, out, 4096, 1024, 1024);
}